// Round 1
// baseline (1250.654 us; speedup 1.0000x reference)
//
#include <hip/hip_runtime.h>

namespace {
constexpr int kS = 16384;
constexpr int kD = 64;
constexpr int kW = 128;          // window overlap w = window_size/2
constexpr int kH = 16;

__global__ __launch_bounds__(128)
void lf_attn_fp32(const float* __restrict__ Q, const float* __restrict__ K,
                  const float* __restrict__ V, const float* __restrict__ M,
                  float* __restrict__ O) {
  const int qb = blockIdx.x;       // query block along S (w-aligned, 128 rows)
  const int h  = blockIdx.y;       // head
  const int t  = threadIdx.x;      // 0..127 -> one query row per thread
  const int s  = qb * kW + t;
  const size_t hb = (size_t)h * kS * kD;

  const float* __restrict__ Kh = K + hb;
  const float* __restrict__ Vh = V + hb;

  // Q row into registers
  float qr[kD];
  {
    const float4* q4 = reinterpret_cast<const float4*>(Q + hb + (size_t)s * kD);
#pragma unroll
    for (int i = 0; i < kD / 4; ++i) {
      float4 v = q4[i];
      qr[4*i+0] = v.x; qr[4*i+1] = v.y; qr[4*i+2] = v.z; qr[4*i+3] = v.w;
    }
  }

  // key window: [kstart, s]; loop bound wave-uniform so K/V loads scalarize
  const int kstart = (qb == 0) ? 0 : (qb - 1) * kW;
  const int kend   = __builtin_amdgcn_readfirstlane(s | 63);

  float m = 12.0f;   // defer-max ratchet baseline
  float l = 0.0f;
  float o[kD];
#pragma unroll
  for (int d = 0; d < kD; ++d) o[d] = 0.0f;

  for (int k = kstart; k <= kend; ++k) {
    const float4* kr = reinterpret_cast<const float4*>(Kh + (size_t)k * kD);
    // 4 independent FMA chains to hide dependent-FMA latency
    float sc0 = 0.f, sc1 = 0.f, sc2 = 0.f, sc3 = 0.f;
#pragma unroll
    for (int i = 0; i < kD / 16; ++i) {
      float4 a = kr[4*i+0];
      float4 b = kr[4*i+1];
      float4 c = kr[4*i+2];
      float4 e = kr[4*i+3];
      sc0 = fmaf(a.x, qr[16*i+ 0], sc0); sc1 = fmaf(a.y, qr[16*i+ 1], sc1);
      sc2 = fmaf(a.z, qr[16*i+ 2], sc2); sc3 = fmaf(a.w, qr[16*i+ 3], sc3);
      sc0 = fmaf(b.x, qr[16*i+ 4], sc0); sc1 = fmaf(b.y, qr[16*i+ 5], sc1);
      sc2 = fmaf(b.z, qr[16*i+ 6], sc2); sc3 = fmaf(b.w, qr[16*i+ 7], sc3);
      sc0 = fmaf(c.x, qr[16*i+ 8], sc0); sc1 = fmaf(c.y, qr[16*i+ 9], sc1);
      sc2 = fmaf(c.z, qr[16*i+10], sc2); sc3 = fmaf(c.w, qr[16*i+11], sc3);
      sc0 = fmaf(e.x, qr[16*i+12], sc0); sc1 = fmaf(e.y, qr[16*i+13], sc1);
      sc2 = fmaf(e.z, qr[16*i+14], sc2); sc3 = fmaf(e.w, qr[16*i+15], sc3);
    }
    float sc = (sc0 + sc1) + (sc2 + sc3);
    sc += M[k];                       // additive padding mask (uniform load)
    sc = (k <= s) ? sc : -1e30f;      // causal mask -> exp() == 0

    // defer-max: rescale only when some lane's score ratchets past m+12
    if (__any(sc > m + 12.0f)) {
      float mn = fmaxf(m, sc);
      float alpha = __expf(m - mn);
      l *= alpha;
#pragma unroll
      for (int d = 0; d < kD; ++d) o[d] *= alpha;
      m = mn;
    }
    float p = __expf(sc - m);
    l += p;

    const float4* vr = reinterpret_cast<const float4*>(Vh + (size_t)k * kD);
#pragma unroll
    for (int i = 0; i < kD / 4; ++i) {
      float4 vv = vr[i];
      o[4*i+0] = fmaf(p, vv.x, o[4*i+0]);
      o[4*i+1] = fmaf(p, vv.y, o[4*i+1]);
      o[4*i+2] = fmaf(p, vv.z, o[4*i+2]);
      o[4*i+3] = fmaf(p, vv.w, o[4*i+3]);
    }
  }

  const float inv = 1.0f / l;
  float4* o4 = reinterpret_cast<float4*>(O + hb + (size_t)s * kD);
#pragma unroll
  for (int i = 0; i < kD / 4; ++i) {
    float4 vv;
    vv.x = o[4*i+0] * inv; vv.y = o[4*i+1] * inv;
    vv.z = o[4*i+2] * inv; vv.w = o[4*i+3] * inv;
    o4[i] = vv;
  }
}
} // namespace

extern "C" void kernel_launch(void* const* d_in, const int* in_sizes, int n_in,
                              void* d_out, int out_size, void* d_ws, size_t ws_size,
                              hipStream_t stream) {
  const float* Q = (const float*)d_in[0];
  const float* K = (const float*)d_in[1];
  const float* V = (const float*)d_in[2];
  const float* M = (const float*)d_in[3];
  float* O = (float*)d_out;
  dim3 grid(kS / kW, kH);   // 128 query blocks x 16 heads
  dim3 block(kW);           // 128 threads = 2 waves, 1 query/thread
  hipLaunchKernelGGL(lf_attn_fp32, grid, block, 0, stream, Q, K, V, M, O);
}

// Round 3
// 258.005 us; speedup vs baseline: 4.8474x; 4.8474x over previous
//
#include <hip/hip_runtime.h>

typedef __attribute__((ext_vector_type(8))) short short8;
typedef __attribute__((ext_vector_type(4))) float f32x4;
typedef __attribute__((ext_vector_type(4))) unsigned int u32x4;

namespace {

constexpr int kS = 16384;
constexpr int kD = 64;
constexpr int kH = 16;
// LDS row strides chosen so stride/16B is ODD -> uniform bank-quad coverage
constexpr int KSTR = 72;   // shorts per K-tile row   (144 B = 9 quads)
constexpr int VSTR = 40;   // shorts per Vt row       (80 B  = 5 quads)
constexpr int PSTR = 68;   // u32 per P row           (272 B = 17 quads)

__device__ inline unsigned short bf16hi(float x) {
  return (unsigned short)(__builtin_bit_cast(unsigned int, x) >> 16);
}
__device__ inline float hipart(float x) {
  return __builtin_bit_cast(float, __builtin_bit_cast(unsigned int, x) & 0xFFFF0000u);
}
// 8 fp32 -> hi/lo bf16 split (truncation; lo captures the residual)
__device__ inline void cvt8(float4 a, float4 b, short8& hi, short8& lo) {
  float f[8] = {a.x, a.y, a.z, a.w, b.x, b.y, b.z, b.w};
#pragma unroll
  for (int i = 0; i < 8; ++i) {
    hi[i] = (short)bf16hi(f[i]);
    lo[i] = (short)bf16hi(f[i] - hipart(f[i]));
  }
}

#define MFMA(a, b, c) __builtin_amdgcn_mfma_f32_16x16x32_bf16(a, b, c, 0, 0, 0)

__global__ __launch_bounds__(256, 2)
void lf_attn_mfma(const float* __restrict__ Q, const float* __restrict__ K,
                  const float* __restrict__ V, const float* __restrict__ M,
                  float* __restrict__ O) {
  __shared__ short Khi[32 * KSTR], Klo[32 * KSTR];
  __shared__ short Vthi[64 * VSTR], Vtlo[64 * VSTR];
  __shared__ unsigned int Pint[4][32 * PSTR];   // per-wave private P (hi|lo<<16)

  const int tid = threadIdx.x;
  const int w  = tid >> 6;        // wave 0..3
  const int l  = tid & 63;
  const int g  = l >> 4;          // 16-lane group 0..3
  const int lk = l & 15;
  const int qs = blockIdx.x * 128;
  const int h  = blockIdx.y;
  const size_t hb = (size_t)h * kS * kD;
  const int klo_ = (qs >= 128) ? qs - 128 : 0;
  const int ntiles = (qs + 128 - klo_) >> 5;   // 4 or 8
  const int qw = qs + w * 32;                  // this wave's first q row

  // ---- Q fragments (hi/lo) straight from global into registers ----
  short8 qhi[2][2], qlo[2][2];
#pragma unroll
  for (int qt = 0; qt < 2; ++qt)
#pragma unroll
    for (int ds = 0; ds < 2; ++ds) {
      const float* qp = Q + hb + (size_t)(qw + 16 * qt + lk) * kD + 32 * ds + 8 * g;
      float4 a = *(const float4*)qp;
      float4 b = *(const float4*)(qp + 4);
      cvt8(a, b, qhi[qt][ds], qlo[qt][ds]);
    }

  f32x4 zero4 = {0.f, 0.f, 0.f, 0.f};
  f32x4 oacc[2][4];
#pragma unroll
  for (int qt = 0; qt < 2; ++qt)
#pragma unroll
    for (int dt = 0; dt < 4; ++dt) oacc[qt][dt] = zero4;
  f32x4 lsum[2] = {zero4, zero4};

  // staging registers (K: row tid>>3, d (tid&7)*8; V: row tid&31, d (tid>>5)*8)
  const int skk = tid >> 3, skd = (tid & 7) * 8;
  const int svk = tid & 31, svd = (tid >> 5) * 8;
  float4 ka0, ka1, va0, va1;

  auto stage_load = [&](int k0) {
    const float* kp = K + hb + (size_t)(k0 + skk) * kD + skd;
    ka0 = *(const float4*)kp;  ka1 = *(const float4*)(kp + 4);
    const float* vp = V + hb + (size_t)(k0 + svk) * kD + svd;
    va0 = *(const float4*)vp;  va1 = *(const float4*)(vp + 4);
  };
  auto stage_write = [&]() {
    short8 h8, l8;
    cvt8(ka0, ka1, h8, l8);
    *(short8*)&Khi[skk * KSTR + skd] = h8;
    *(short8*)&Klo[skk * KSTR + skd] = l8;
    cvt8(va0, va1, h8, l8);
#pragma unroll
    for (int j = 0; j < 8; ++j) {
      Vthi[(svd + j) * VSTR + svk] = h8[j];
      Vtlo[(svd + j) * VSTR + svk] = l8[j];
    }
  };

  // prologue: stage tile 0
  stage_load(klo_);
  stage_write();
  __syncthreads();

  for (int tt = 0; tt < ntiles; ++tt) {
    const int k0 = klo_ + tt * 32;
    const bool have_next = (tt + 1 < ntiles);
    if (have_next) stage_load(klo_ + (tt + 1) * 32);   // issue early (T14)

    if (k0 <= qw + 31) {   // wave-uniform skip of fully-masked tiles
      // ---- QK^T: 3-way hi/lo split ----
      f32x4 sacc[2][2];
#pragma unroll
      for (int qt = 0; qt < 2; ++qt)
#pragma unroll
        for (int kt = 0; kt < 2; ++kt) sacc[qt][kt] = zero4;
#pragma unroll
      for (int kt = 0; kt < 2; ++kt)
#pragma unroll
        for (int ds = 0; ds < 2; ++ds) {
          short8 kh = *(const short8*)&Khi[(16 * kt + lk) * KSTR + 32 * ds + 8 * g];
          short8 kl = *(const short8*)&Klo[(16 * kt + lk) * KSTR + 32 * ds + 8 * g];
#pragma unroll
          for (int qt = 0; qt < 2; ++qt) {
            sacc[qt][kt] = MFMA(qhi[qt][ds], kh, sacc[qt][kt]);
            sacc[qt][kt] = MFMA(qhi[qt][ds], kl, sacc[qt][kt]);
            sacc[qt][kt] = MFMA(qlo[qt][ds], kh, sacc[qt][kt]);
          }
        }

      // ---- softmax (no-max: scores bounded << 88) + pack P hi/lo ----
      const float mv0 = M[k0 + lk];
      const float mv1 = M[k0 + 16 + lk];
#pragma unroll
      for (int qt = 0; qt < 2; ++qt) {
        f32x4 pr[2];
#pragma unroll
        for (int kt = 0; kt < 2; ++kt) {
          const int kg = k0 + 16 * kt + lk;
          const float mv = kt ? mv1 : mv0;
          f32x4 p;
#pragma unroll
          for (int r = 0; r < 4; ++r) {
            const int qg = qw + 16 * qt + 4 * g + r;
            p[r] = (kg <= qg) ? __expf(sacc[qt][kt][r] + mv) : 0.f;
          }
          pr[kt] = p;
#pragma unroll
          for (int r = 0; r < 4; ++r) {
            unsigned hh = bf16hi(p[r]);
            unsigned ll = bf16hi(p[r] - hipart(p[r]));
            Pint[w][(16 * qt + 4 * g + r) * PSTR + 16 * kt + lk] = hh | (ll << 16);
          }
        }
        f32x4 rs = pr[0] + pr[1];
#pragma unroll
        for (int m = 1; m <= 8; m <<= 1) {
#pragma unroll
          for (int r = 0; r < 4; ++r) rs[r] += __shfl_xor(rs[r], m, 64);
        }
        lsum[qt] += rs;
      }

      // ---- PV: 3-way hi/lo split ----
      short8 vh[4], vl[4];
#pragma unroll
      for (int dt = 0; dt < 4; ++dt) {
        vh[dt] = *(const short8*)&Vthi[(16 * dt + lk) * VSTR + 8 * g];
        vl[dt] = *(const short8*)&Vtlo[(16 * dt + lk) * VSTR + 8 * g];
      }
#pragma unroll
      for (int qt = 0; qt < 2; ++qt) {
        const unsigned int* prow = &Pint[w][(16 * qt + lk) * PSTR + 8 * g];
        u32x4 x0 = *(const u32x4*)prow;
        u32x4 x1 = *(const u32x4*)(prow + 4);
        u32x4 hu, lu;
        hu[0] = __builtin_amdgcn_perm(x0[1], x0[0], 0x05040100u);
        lu[0] = __builtin_amdgcn_perm(x0[1], x0[0], 0x07060302u);
        hu[1] = __builtin_amdgcn_perm(x0[3], x0[2], 0x05040100u);
        lu[1] = __builtin_amdgcn_perm(x0[3], x0[2], 0x07060302u);
        hu[2] = __builtin_amdgcn_perm(x1[1], x1[0], 0x05040100u);
        lu[2] = __builtin_amdgcn_perm(x1[1], x1[0], 0x07060302u);
        hu[3] = __builtin_amdgcn_perm(x1[3], x1[2], 0x05040100u);
        lu[3] = __builtin_amdgcn_perm(x1[3], x1[2], 0x07060302u);
        short8 ph = __builtin_bit_cast(short8, hu);
        short8 pl = __builtin_bit_cast(short8, lu);
#pragma unroll
        for (int dt = 0; dt < 4; ++dt) {
          oacc[qt][dt] = MFMA(ph, vh[dt], oacc[qt][dt]);
          oacc[qt][dt] = MFMA(pl, vh[dt], oacc[qt][dt]);
          oacc[qt][dt] = MFMA(ph, vl[dt], oacc[qt][dt]);
        }
      }
    }

    __syncthreads();                    // all waves done reading K/Vt
    if (have_next) stage_write();       // overwrite single buffer
    __syncthreads();                    // writes visible
  }

  // ---- epilogue: normalize and store ----
#pragma unroll
  for (int qt = 0; qt < 2; ++qt) {
    f32x4 inv;
#pragma unroll
    for (int r = 0; r < 4; ++r) inv[r] = 1.0f / lsum[qt][r];
#pragma unroll
    for (int dt = 0; dt < 4; ++dt)
#pragma unroll
      for (int r = 0; r < 4; ++r)
        O[hb + (size_t)(qw + 16 * qt + 4 * g + r) * kD + 16 * dt + lk] =
            oacc[qt][dt][r] * inv[r];
  }
}

} // namespace

extern "C" void kernel_launch(void* const* d_in, const int* in_sizes, int n_in,
                              void* d_out, int out_size, void* d_ws, size_t ws_size,
                              hipStream_t stream) {
  const float* Q = (const float*)d_in[0];
  const float* K = (const float*)d_in[1];
  const float* V = (const float*)d_in[2];
  const float* M = (const float*)d_in[3];
  float* O = (float*)d_out;
  dim3 grid(kS / 128, kH);
  dim3 block(256);
  hipLaunchKernelGGL(lf_attn_mfma, grid, block, 0, stream, Q, K, V, M, O);
}